// Round 3
// baseline (208.402 us; speedup 1.0000x reference)
//
#include <hip/hip_runtime.h>
#include <hip/hip_bf16.h>
#include <hip/hip_fp16.h>
#include <cstddef>

// Problem constants
#define NB 2
#define QN 12240
#define SN 12240
#define MREAL 24480          // NB*QN rows
#define MPAD  24576          // 192 * 128
#define MT    192            // M tiles of 128

typedef unsigned short ushortT;
typedef unsigned int uintT;
typedef __bf16 bf16x8 __attribute__((ext_vector_type(8)));
typedef float f32x4 __attribute__((ext_vector_type(4)));
typedef float f32x2 __attribute__((ext_vector_type(2)));

__device__ __forceinline__ ushortT f2bf(float f) {
    uintT u = __float_as_uint(f);
    uintT r = u + 0x7fffu + ((u >> 16) & 1u);   // RNE
    return (ushortT)(r >> 16);
}
__device__ __forceinline__ float bf_lo(uintT u) {   // low bf16 -> f32
    return __uint_as_float(u << 16);
}
__device__ __forceinline__ float bf_hi(uintT u) {   // high bf16 -> f32
    return __uint_as_float(u & 0xffff0000u);
}

__device__ __forceinline__ void async_ld16(const ushortT* g, ushortT* l) {
    __builtin_amdgcn_global_load_lds(
        (const __attribute__((address_space(1))) unsigned int*)g,
        (__attribute__((address_space(3))) unsigned int*)l, 16, 0, 0);
}

// ---------------------------------------------------------------------------
// Merged cast kernel.
// bx in [0,3060): queries -> q_bf (bf16)
// bx in [3060,6120): src -> src_bf
// bx in [6120,7016): weight cast+transpose (W_val/W_attn/W_off/W_out)
// ---------------------------------------------------------------------------
__global__ __launch_bounds__(256) void cast_all(
    const float* __restrict__ q, const float* __restrict__ src,
    const float* __restrict__ Wval, const float* __restrict__ Wattn,
    const float* __restrict__ Woff, const float* __restrict__ Wout,
    ushortT* __restrict__ qb, ushortT* __restrict__ sb,
    ushortT* __restrict__ tval, ushortT* __restrict__ tlo,
    ushortT* __restrict__ tout)
{
    int bx = blockIdx.x;
    if (bx < 6120) {
        const int issrc = bx >= 3060;
        const size_t idx = ((size_t)(bx - (issrc ? 3060 : 0)) * 256 + threadIdx.x) * 8;
        const float* in = issrc ? src : q;
        ushortT* out = issrc ? sb : qb;
        const float4 a = *(const float4*)(in + idx);
        const float4 b = *(const float4*)(in + idx + 4);
        uint4 o;
        o.x = (uintT)f2bf(a.x) | ((uintT)f2bf(a.y) << 16);
        o.y = (uintT)f2bf(a.z) | ((uintT)f2bf(a.w) << 16);
        o.z = (uintT)f2bf(b.x) | ((uintT)f2bf(b.y) << 16);
        o.w = (uintT)f2bf(b.z) | ((uintT)f2bf(b.w) << 16);
        *(uint4*)(out + idx) = o;
        return;
    }
    bx -= 6120;
    const float* W; ushortT* T; int n, Nw, trow;
    if (bx < 256)      { W = Wval;  T = tval; n = bx;       Nw = 256; trow = n; }
    else if (bx < 384) { W = Wattn; T = tlo;  n = bx - 256; Nw = 128; trow = n; }
    else if (bx < 640) { W = Woff;  T = tlo;  n = bx - 384; Nw = 256; trow = n + 128; }
    else               { W = Wout;  T = tout; n = bx - 640; Nw = 256; trow = n; }
    const int k = threadIdx.x;
    T[(size_t)trow * 256 + k] = f2bf(W[(size_t)k * Nw + n]);
}

// ---------------------------------------------------------------------------
// Fused v + (logits|off) GEMM, LDS-staged (R5 structure), flat grid.
// bx<2: v = src@W_val -> v_bf in HEAD-MAJOR layout (n, head, s, 32ch) bf16
// bx>=2: lo = q@[W_attn;W_off] (col0=(bx-2)*128, fp32 out, Ntot=384)
// ---------------------------------------------------------------------------
__global__ __launch_bounds__(256) void gemm_vlo(
    const ushortT* __restrict__ q_bf, const ushortT* __restrict__ src_bf,
    const ushortT* __restrict__ wt_val, const ushortT* __restrict__ wt_lo,
    const float* __restrict__ b_val, const float* __restrict__ b_attn,
    const float* __restrict__ b_off,
    ushortT* __restrict__ v_bf, float* __restrict__ lo_ws)
{
    const int z = blockIdx.x >= 2;
    const int col0 = (z ? blockIdx.x - 2 : blockIdx.x) * 128;

    __shared__ __attribute__((aligned(16))) ushortT As[128 * 32];
    __shared__ __attribute__((aligned(16))) ushortT Bs[128 * 32];

    const ushortT* A  = z ? q_bf : src_bf;
    const ushortT* Bt = z ? wt_lo : wt_val;

    const int tid  = threadIdx.x;
    const int wave = tid >> 6;
    const int lane = tid & 63;
    const int row0 = blockIdx.y * 128;
    const int wr = (wave >> 1) * 64;
    const int wc = (wave & 1) * 64;

    f32x4 acc[4][4];
    #pragma unroll
    for (int i = 0; i < 4; i++)
        #pragma unroll
        for (int j = 0; j < 4; j++)
            acc[i][j] = (f32x4)0.f;

    const int srow = (lane >> 2);
    const int sk8  = (lane & 3) * 8;

    for (int k0 = 0; k0 < 256; k0 += 32) {
        #pragma unroll
        for (int j = 0; j < 2; j++) {
            const int r = wave * 32 + j * 16;
            async_ld16(A  + (size_t)(row0 + r + srow) * 256 + k0 + sk8, &As[r * 32]);
            async_ld16(Bt + (size_t)(col0 + r + srow) * 256 + k0 + sk8, &Bs[r * 32]);
        }
        __syncthreads();

        bf16x8 af[4], bfr[4];
        const int mrow = lane & 15;
        const int kq   = (lane >> 4) * 8;
        #pragma unroll
        for (int i = 0; i < 4; i++) {
            af[i]  = *(const bf16x8*)&As[(wr + i * 16 + mrow) * 32 + kq];
            bfr[i] = *(const bf16x8*)&Bs[(wc + i * 16 + mrow) * 32 + kq];
        }
        #pragma unroll
        for (int i = 0; i < 4; i++)
            #pragma unroll
            for (int j = 0; j < 4; j++)
                acc[i][j] = __builtin_amdgcn_mfma_f32_16x16x32_bf16(
                    af[i], bfr[j], acc[i][j], 0, 0, 0);
        __syncthreads();
    }

    const float* bp = z ? ((col0 < 128) ? b_attn : b_off) : b_val;
    const int cofs  = (z && col0 >= 128) ? 128 : 0;

    #pragma unroll
    for (int i = 0; i < 4; i++) {
        const int rbase = row0 + wr + i * 16 + ((lane >> 4) << 2);
        #pragma unroll
        for (int j = 0; j < 4; j++) {
            const int col = col0 + wc + j * 16 + (lane & 15);
            const float bb = bp[col - cofs];
            #pragma unroll
            for (int r = 0; r < 4; r++) {
                const int row = rbase + r;
                if (row < MREAL) {
                    const float val = acc[i][j][r] + bb;
                    if (z) {
                        lo_ws[(size_t)row * 384 + col] = val;
                    } else {
                        // head-major v: (n, head, s, ch)
                        const int nn = row / SN;
                        const int s  = row - nn * SN;
                        const int head = col >> 5, ch = col & 31;
                        v_bf[(((size_t)nn * 8 + head) * SN + s) * 32 + ch] = f2bf(val);
                    }
                }
            }
        }
    }
}

// ---------------------------------------------------------------------------
// Out GEMM (R5 LDS structure): out = mdv(bf16) @ wt_out^T + b_out (fp32).
// ---------------------------------------------------------------------------
__global__ __launch_bounds__(256) void gemm_out(
    const ushortT* __restrict__ A, const ushortT* __restrict__ Bt,
    const float* __restrict__ bias, float* __restrict__ C)
{
    __shared__ __attribute__((aligned(16))) ushortT As[128 * 32];
    __shared__ __attribute__((aligned(16))) ushortT Bs[128 * 32];

    const int tid  = threadIdx.x;
    const int wave = tid >> 6;
    const int lane = tid & 63;
    const int row0 = blockIdx.y * 128;
    const int col0 = blockIdx.x * 128;
    const int wr = (wave >> 1) * 64;
    const int wc = (wave & 1) * 64;

    f32x4 acc[4][4];
    #pragma unroll
    for (int i = 0; i < 4; i++)
        #pragma unroll
        for (int j = 0; j < 4; j++)
            acc[i][j] = (f32x4)0.f;

    const int srow = (lane >> 2);
    const int sk8  = (lane & 3) * 8;

    for (int k0 = 0; k0 < 256; k0 += 32) {
        #pragma unroll
        for (int j = 0; j < 2; j++) {
            const int r = wave * 32 + j * 16;
            async_ld16(A  + (size_t)(row0 + r + srow) * 256 + k0 + sk8, &As[r * 32]);
            async_ld16(Bt + (size_t)(col0 + r + srow) * 256 + k0 + sk8, &Bs[r * 32]);
        }
        __syncthreads();

        bf16x8 af[4], bfr[4];
        const int mrow = lane & 15;
        const int kq   = (lane >> 4) * 8;
        #pragma unroll
        for (int i = 0; i < 4; i++) {
            af[i]  = *(const bf16x8*)&As[(wr + i * 16 + mrow) * 32 + kq];
            bfr[i] = *(const bf16x8*)&Bs[(wc + i * 16 + mrow) * 32 + kq];
        }
        #pragma unroll
        for (int i = 0; i < 4; i++)
            #pragma unroll
            for (int j = 0; j < 4; j++)
                acc[i][j] = __builtin_amdgcn_mfma_f32_16x16x32_bf16(
                    af[i], bfr[j], acc[i][j], 0, 0, 0);
        __syncthreads();
    }

    #pragma unroll
    for (int i = 0; i < 4; i++) {
        const int rbase = row0 + wr + i * 16 + ((lane >> 4) << 2);
        #pragma unroll
        for (int j = 0; j < 4; j++) {
            const int col = col0 + wc + j * 16 + (lane & 15);
            const float bb = bias[col];
            #pragma unroll
            for (int r = 0; r < 4; r++) {
                const int row = rbase + r;
                if (row < MREAL)
                    C[(size_t)row * 256 + col] = acc[i][j][r] + bb;
            }
        }
    }
}

// ---------------------------------------------------------------------------
// Per-head two-phase sample kernel. Block = 256 threads = 4 waves =
// 32 queries of ONE head (grid: 383 x 8 heads x 2 batch; tail block
// clamps q -> benign duplicate writes of identical values). The 128-thread
// config measured only ~8 WGs/CU resident (52% occupancy) -- the gather
// phase is concurrency-bound (Little's law: ~100 loads in flight needed),
// so 4-wave WGs raise resident waves within whatever WG-slot cap exists.
// LDS 25.1 KB -> 6 WGs by LDS = 24 waves/CU.
// Phase 1 (lane=(qi,p)): softmax via shfl over 8 p-lanes; per point ONE
//   48B LDS record {int4 fully-resolved byte offsets,
//                   float4 {w00,w00,w10,w10}, float4 {w01,w01,w11,w11}}.
//   Records stored in pt = t*8+p order (stride 12 ints per p -> odd
//   bank-quad coefficient -> zero write conflicts, verified R2).
// Phase 2 (lane=(qi,c)): 4 groups of 4 points. Per group: 4x ds_read_b128
//   offsets, 16 8B gathers back-to-back, then weights + v_pk_fma_f32.
// ---------------------------------------------------------------------------
__global__ __launch_bounds__(256) void sample_kernel(
    const float* __restrict__ lo,       // (N*Q, 384): [0,128) logits, [128,384) off
    const float* __restrict__ geom,     // (N*Q, 4)
    const ushortT* __restrict__ v,      // (N, 8, S, 32) bf16 head-major
    ushortT* __restrict__ out)          // (N*Q, 256) bf16 mdv
{
    const int tid  = threadIdx.x;
    const int w    = tid >> 6;          // wave 0..3
    const int lane = tid & 63;
    const int qi   = lane >> 3;         // query within wave's 8
    const int m    = blockIdx.y;        // head
    const int n    = blockIdx.z;
    int q = blockIdx.x * 32 + w * 8 + qi;
    q = min(q, QN - 1);                 // tail clamp (duplicates are benign)

    // per query: 16 points * 12 ints + 4 pad = 196 ints (stride = 4 banks)
    __shared__ __attribute__((aligned(16))) int pls[4][1568];   // 25088 B

    const size_t qb = (size_t)n * QN + q;

    // ---- phase 1 ----
    {
        const int p = lane & 7;                  // point pair 0..7
        const float* lorow = lo + qb * 384;
        const float2 lg = *(const float2*)(lorow + m * 16 + p * 2);
        const float4 of = *(const float4*)(lorow + 128 + m * 32 + p * 4);
        const float4 g  = *(const float4*)(geom + qb * 4);

        float mx = fmaxf(lg.x, lg.y);
        mx = fmaxf(mx, __shfl_xor(mx, 1));
        mx = fmaxf(mx, __shfl_xor(mx, 2));
        mx = fmaxf(mx, __shfl_xor(mx, 4));
        const float e0 = __expf(lg.x - mx);
        const float e1 = __expf(lg.y - mx);
        float s = e0 + e1;
        s += __shfl_xor(s, 1);
        s += __shfl_xor(s, 2);
        s += __shfl_xor(s, 4);
        const float inv = 1.f / s;

        const int l  = p >> 1;
        const int Wl = 96 >> l;
        const int s0 = (l == 0) ? 0 : (l == 1) ? 9216 : (l == 2) ? 11520 : 12096;
        const float cx = g.x, cy = g.y;
        const float sx = g.z * 0.125f, sy = g.w * 0.125f;
        // record for point pt = t*8 + p lives at qi*196 + pt*12
        int* myrec = &pls[w][qi * 196 + p * 12];

        #pragma unroll
        for (int t = 0; t < 2; t++) {
            const float ox = t ? of.z : of.x;
            const float oy = t ? of.w : of.y;
            const float wa = (t ? e1 : e0) * inv;

            const float x = (cx + ox * sx) * (float)Wl - 0.5f;
            const float y = (cy + oy * sy) * (float)Wl - 0.5f;
            const float xf = floorf(x), yf = floorf(y);
            const int x0 = (int)xf, y0 = (int)yf;
            const float wx = x - xf, wy = y - yf;

            const bool vx0 = (x0 >= 0) & (x0 < Wl);
            const bool vx1 = (x0 + 1 >= 0) & (x0 + 1 < Wl);
            const bool vy0 = (y0 >= 0) & (y0 < Wl);
            const bool vy1 = (y0 + 1 >= 0) & (y0 + 1 < Wl);

            const float w00 = (vx0 & vy0) ? wa * (1.f - wx) * (1.f - wy) : 0.f;
            const float w10 = (vx1 & vy0) ? wa * wx * (1.f - wy) : 0.f;
            const float w01 = (vx0 & vy1) ? wa * (1.f - wx) * wy : 0.f;
            const float w11 = (vx1 & vy1) ? wa * wx * wy : 0.f;

            const int xc0 = min(max(x0, 0), Wl - 1);
            const int xc1 = min(max(x0 + 1, 0), Wl - 1);
            const int yc0 = min(max(y0, 0), Wl - 1);
            const int yc1 = min(max(y0 + 1, 0), Wl - 1);

            const int o00 = (s0 + yc0 * Wl + xc0) << 6;     // byte off, row 64B
            const int dx  = (xc1 - xc0) << 6;               // 0 or 64
            const int dy  = ((yc1 - yc0) * Wl) << 6;        // 0..6144

            int4 offs;
            offs.x = o00;
            offs.y = o00 + dx;
            offs.z = o00 + dy;
            offs.w = o00 + dy + dx;
            float4 wab, wcd;
            wab.x = w00; wab.y = w00; wab.z = w10; wab.w = w10;
            wcd.x = w01; wcd.y = w01; wcd.z = w11; wcd.w = w11;

            int* rp = myrec + t * 96;       // pt = t*8 + p
            *(int4*)rp = offs;
            *(float4*)(rp + 4) = wab;
            *(float4*)(rp + 8) = wcd;
        }
    }
    __syncthreads();

    // ---- phase 2 ----
    const int c  = lane & 7;            // channel quad within head
    const unsigned c8 = (unsigned)(c * 8);
    const unsigned char* vp = (const unsigned char*)
        (v + ((size_t)(n * 8 + m) * SN) * 32);              // uniform base
    const int* grec = &pls[w][qi * 196];

    f32x2 acc01 = (f32x2)0.f, acc23 = (f32x2)0.f;

    #pragma unroll
    for (int g = 0; g < 4; g++) {
        const int* r0 = grec + (g * 4 + 0) * 12;
        const int* r1 = grec + (g * 4 + 1) * 12;
        const int* r2 = grec + (g * 4 + 2) * 12;
        const int* r3 = grec + (g * 4 + 3) * 12;

        // 4 offset quads from LDS
        const int4 o0 = *(const int4*)r0;
        const int4 o1 = *(const int4*)r1;
        const int4 o2 = *(const int4*)r2;
        const int4 o3 = *(const int4*)r3;

        // 16 independent gathers, issued back-to-back
        const uint2 u00 = *(const uint2*)(vp + ((unsigned)o0.x + c8));
        const uint2 u01 = *(const uint2*)(vp + ((unsigned)o0.y + c8));
        const uint2 u02 = *(const uint2*)(vp + ((unsigned)o0.z + c8));
        const uint2 u03 = *(const uint2*)(vp + ((unsigned)o0.w + c8));
        const uint2 u10 = *(const uint2*)(vp + ((unsigned)o1.x + c8));
        const uint2 u11 = *(const uint2*)(vp + ((unsigned)o1.y + c8));
        const uint2 u12 = *(const uint2*)(vp + ((unsigned)o1.z + c8));
        const uint2 u13 = *(const uint2*)(vp + ((unsigned)o1.w + c8));
        const uint2 u20 = *(const uint2*)(vp + ((unsigned)o2.x + c8));
        const uint2 u21 = *(const uint2*)(vp + ((unsigned)o2.y + c8));
        const uint2 u22 = *(const uint2*)(vp + ((unsigned)o2.z + c8));
        const uint2 u23 = *(const uint2*)(vp + ((unsigned)o2.w + c8));
        const uint2 u30 = *(const uint2*)(vp + ((unsigned)o3.x + c8));
        const uint2 u31 = *(const uint2*)(vp + ((unsigned)o3.y + c8));
        const uint2 u32 = *(const uint2*)(vp + ((unsigned)o3.z + c8));
        const uint2 u33 = *(const uint2*)(vp + ((unsigned)o3.w + c8));

        // weights (duplicated f32 pairs) + FMAs per record
        {
            const f32x2* wp = (const f32x2*)(r0 + 4);
            const f32x2 wA = wp[0], wB = wp[1], wC = wp[2], wD = wp[3];
            f32x2 t;
            t.x = bf_lo(u00.x); t.y = bf_hi(u00.x); acc01 += wA * t;
            t.x = bf_lo(u00.y); t.y = bf_hi(u00.y); acc23 += wA * t;
            t.x = bf_lo(u01.x); t.y = bf_hi(u01.x); acc01 += wB * t;
            t.x = bf_lo(u01.y); t.y = bf_hi(u01.y); acc23 += wB * t;
            t.x = bf_lo(u02.x); t.y = bf_hi(u02.x); acc01 += wC * t;
            t.x = bf_lo(u02.y); t.y = bf_hi(u02.y); acc23 += wC * t;
            t.x = bf_lo(u03.x); t.y = bf_hi(u03.x); acc01 += wD * t;
            t.x = bf_lo(u03.y); t.y = bf_hi(u03.y); acc23 += wD * t;
        }
        {
            const f32x2* wp = (const f32x2*)(r1 + 4);
            const f32x2 wA = wp[0], wB = wp[1], wC = wp[2], wD = wp[3];
            f32x2 t;
            t.x = bf_lo(u10.x); t.y = bf_hi(u10.x); acc01 += wA * t;
            t.x = bf_lo(u10.y); t.y = bf_hi(u10.y); acc23 += wA * t;
            t.x = bf_lo(u11.x); t.y = bf_hi(u11.x); acc01 += wB * t;
            t.x = bf_lo(u11.y); t.y = bf_hi(u11.y); acc23 += wB * t;
            t.x = bf_lo(u12.x); t.y = bf_hi(u12.x); acc01 += wC * t;
            t.x = bf_lo(u12.y); t.y = bf_hi(u12.y); acc23 += wC * t;
            t.x = bf_lo(u13.x); t.y = bf_hi(u13.x); acc01 += wD * t;
            t.x = bf_lo(u13.y); t.y = bf_hi(u13.y); acc23 += wD * t;
        }
        {
            const f32x2* wp = (const f32x2*)(r2 + 4);
            const f32x2 wA = wp[0], wB = wp[1], wC = wp[2], wD = wp[3];
            f32x2 t;
            t.x = bf_lo(u20.x); t.y = bf_hi(u20.x); acc01 += wA * t;
            t.x = bf_lo(u20.y); t.y = bf_hi(u20.y); acc23 += wA * t;
            t.x = bf_lo(u21.x); t.y = bf_hi(u21.x); acc01 += wB * t;
            t.x = bf_lo(u21.y); t.y = bf_hi(u21.y); acc23 += wB * t;
            t.x = bf_lo(u22.x); t.y = bf_hi(u22.x); acc01 += wC * t;
            t.x = bf_lo(u22.y); t.y = bf_hi(u22.y); acc23 += wC * t;
            t.x = bf_lo(u23.x); t.y = bf_hi(u23.x); acc01 += wD * t;
            t.x = bf_lo(u23.y); t.y = bf_hi(u23.y); acc23 += wD * t;
        }
        {
            const f32x2* wp = (const f32x2*)(r3 + 4);
            const f32x2 wA = wp[0], wB = wp[1], wC = wp[2], wD = wp[3];
            f32x2 t;
            t.x = bf_lo(u30.x); t.y = bf_hi(u30.x); acc01 += wA * t;
            t.x = bf_lo(u30.y); t.y = bf_hi(u30.y); acc23 += wA * t;
            t.x = bf_lo(u31.x); t.y = bf_hi(u31.x); acc01 += wB * t;
            t.x = bf_lo(u31.y); t.y = bf_hi(u31.y); acc23 += wB * t;
            t.x = bf_lo(u32.x); t.y = bf_hi(u32.x); acc01 += wC * t;
            t.x = bf_lo(u32.y); t.y = bf_hi(u32.y); acc23 += wC * t;
            t.x = bf_lo(u33.x); t.y = bf_hi(u33.x); acc01 += wD * t;
            t.x = bf_lo(u33.y); t.y = bf_hi(u33.y); acc23 += wD * t;
        }
    }

    ushort4 o;
    o.x = f2bf(acc01.x); o.y = f2bf(acc01.y); o.z = f2bf(acc23.x); o.w = f2bf(acc23.y);
    *(ushort4*)(out + qb * 256 + m * 32 + c * 4) = o;
}

// ---------------------------------------------------------------------------
extern "C" void kernel_launch(void* const* d_in, const int* in_sizes, int n_in,
                              void* d_out, int out_size, void* d_ws, size_t ws_size,
                              hipStream_t stream)
{
    const float* queries = (const float*)d_in[0];
    const float* geom    = (const float*)d_in[1];
    const float* src     = (const float*)d_in[2];
    const float* W_off   = (const float*)d_in[3];
    const float* b_off   = (const float*)d_in[4];
    const float* W_attn  = (const float*)d_in[5];
    const float* b_attn  = (const float*)d_in[6];
    const float* W_val   = (const float*)d_in[7];
    const float* b_val   = (const float*)d_in[8];
    const float* W_out   = (const float*)d_in[9];
    const float* b_out   = (const float*)d_in[10];
    float* out = (float*)d_out;

    ushortT* wsb = (ushortT*)d_ws;
    const size_t PADROW = (size_t)MPAD * 256;          // 6,291,456 elems
    ushortT* q_bf    = wsb;
    ushortT* srcmdv  = wsb + PADROW;                   // src_bf, later mdv_bf
    ushortT* v_bf    = wsb + 2 * PADROW;               // head-major v
    ushortT* wt_val  = wsb + 3 * PADROW;               // 256*256
    ushortT* wt_lo   = wt_val + 65536;                 // 384*256
    ushortT* wt_out  = wt_lo + 98304;                  // 256*256
    float* lo_ws = (float*)(wt_out + 65536);           // 24480*384 fp32
    // total ~75.8 MB

    dim3 blk(256);

    cast_all<<<dim3(7016), blk, 0, stream>>>(
        queries, src, W_val, W_attn, W_off, W_out,
        q_bf, srcmdv, wt_val, wt_lo, wt_out);

    // bx<2: v = src@W_val -> v_bf (bf16 head-major); bx>=2: lo -> lo_ws
    gemm_vlo<<<dim3(5, MT), blk, 0, stream>>>(
        q_bf, srcmdv, wt_val, wt_lo, b_val, b_attn, b_off, v_bf, lo_ws);

    sample_kernel<<<dim3((QN + 31) / 32, 8, NB), dim3(256), 0, stream>>>(
        lo_ws, geom, v_bf, srcmdv);

    gemm_out<<<dim3(2, MT), blk, 0, stream>>>(srcmdv, wt_out, b_out, out);
}

// Round 4
// 207.129 us; speedup vs baseline: 1.0061x; 1.0061x over previous
//
#include <hip/hip_runtime.h>
#include <hip/hip_bf16.h>
#include <hip/hip_fp16.h>
#include <cstddef>

// Problem constants
#define NB 2
#define QN 12240
#define SN 12240
#define MREAL 24480          // NB*QN rows
#define MPAD  24576          // 192 * 128
#define MT    192            // M tiles of 128

typedef unsigned short ushortT;
typedef unsigned int uintT;
typedef __bf16 bf16x8 __attribute__((ext_vector_type(8)));
typedef float f32x4 __attribute__((ext_vector_type(4)));
typedef float f32x2 __attribute__((ext_vector_type(2)));

__device__ __forceinline__ ushortT f2bf(float f) {
    uintT u = __float_as_uint(f);
    uintT r = u + 0x7fffu + ((u >> 16) & 1u);   // RNE
    return (ushortT)(r >> 16);
}
__device__ __forceinline__ float bf_lo(uintT u) {   // low bf16 -> f32
    return __uint_as_float(u << 16);
}
__device__ __forceinline__ float bf_hi(uintT u) {   // high bf16 -> f32
    return __uint_as_float(u & 0xffff0000u);
}

__device__ __forceinline__ void async_ld16(const ushortT* g, ushortT* l) {
    __builtin_amdgcn_global_load_lds(
        (const __attribute__((address_space(1))) unsigned int*)g,
        (__attribute__((address_space(3))) unsigned int*)l, 16, 0, 0);
}

// ---------------------------------------------------------------------------
// Merged cast kernel.
// bx in [0,3060): queries -> q_bf (bf16)
// bx in [3060,6120): src -> src_bf
// bx in [6120,7016): weight cast+transpose (W_val/W_attn/W_off/W_out)
// ---------------------------------------------------------------------------
__global__ __launch_bounds__(256) void cast_all(
    const float* __restrict__ q, const float* __restrict__ src,
    const float* __restrict__ Wval, const float* __restrict__ Wattn,
    const float* __restrict__ Woff, const float* __restrict__ Wout,
    ushortT* __restrict__ qb, ushortT* __restrict__ sb,
    ushortT* __restrict__ tval, ushortT* __restrict__ tlo,
    ushortT* __restrict__ tout)
{
    int bx = blockIdx.x;
    if (bx < 6120) {
        const int issrc = bx >= 3060;
        const size_t idx = ((size_t)(bx - (issrc ? 3060 : 0)) * 256 + threadIdx.x) * 8;
        const float* in = issrc ? src : q;
        ushortT* out = issrc ? sb : qb;
        const float4 a = *(const float4*)(in + idx);
        const float4 b = *(const float4*)(in + idx + 4);
        uint4 o;
        o.x = (uintT)f2bf(a.x) | ((uintT)f2bf(a.y) << 16);
        o.y = (uintT)f2bf(a.z) | ((uintT)f2bf(a.w) << 16);
        o.z = (uintT)f2bf(b.x) | ((uintT)f2bf(b.y) << 16);
        o.w = (uintT)f2bf(b.z) | ((uintT)f2bf(b.w) << 16);
        *(uint4*)(out + idx) = o;
        return;
    }
    bx -= 6120;
    const float* W; ushortT* T; int n, Nw, trow;
    if (bx < 256)      { W = Wval;  T = tval; n = bx;       Nw = 256; trow = n; }
    else if (bx < 384) { W = Wattn; T = tlo;  n = bx - 256; Nw = 128; trow = n; }
    else if (bx < 640) { W = Woff;  T = tlo;  n = bx - 384; Nw = 256; trow = n + 128; }
    else               { W = Wout;  T = tout; n = bx - 640; Nw = 256; trow = n; }
    const int k = threadIdx.x;
    T[(size_t)trow * 256 + k] = f2bf(W[(size_t)k * Nw + n]);
}

// ---------------------------------------------------------------------------
// Fused v + (logits|off) GEMM, LDS-staged (R5 structure), flat grid.
// bx<2: v = src@W_val -> v_bf in HEAD-MAJOR layout (n, head, s, 32ch) bf16
// bx>=2: lo = q@[W_attn;W_off] (col0=(bx-2)*128, fp32 out, Ntot=384)
// ---------------------------------------------------------------------------
__global__ __launch_bounds__(256) void gemm_vlo(
    const ushortT* __restrict__ q_bf, const ushortT* __restrict__ src_bf,
    const ushortT* __restrict__ wt_val, const ushortT* __restrict__ wt_lo,
    const float* __restrict__ b_val, const float* __restrict__ b_attn,
    const float* __restrict__ b_off,
    ushortT* __restrict__ v_bf, float* __restrict__ lo_ws)
{
    const int z = blockIdx.x >= 2;
    const int col0 = (z ? blockIdx.x - 2 : blockIdx.x) * 128;

    __shared__ __attribute__((aligned(16))) ushortT As[128 * 32];
    __shared__ __attribute__((aligned(16))) ushortT Bs[128 * 32];

    const ushortT* A  = z ? q_bf : src_bf;
    const ushortT* Bt = z ? wt_lo : wt_val;

    const int tid  = threadIdx.x;
    const int wave = tid >> 6;
    const int lane = tid & 63;
    const int row0 = blockIdx.y * 128;
    const int wr = (wave >> 1) * 64;
    const int wc = (wave & 1) * 64;

    f32x4 acc[4][4];
    #pragma unroll
    for (int i = 0; i < 4; i++)
        #pragma unroll
        for (int j = 0; j < 4; j++)
            acc[i][j] = (f32x4)0.f;

    const int srow = (lane >> 2);
    const int sk8  = (lane & 3) * 8;

    for (int k0 = 0; k0 < 256; k0 += 32) {
        #pragma unroll
        for (int j = 0; j < 2; j++) {
            const int r = wave * 32 + j * 16;
            async_ld16(A  + (size_t)(row0 + r + srow) * 256 + k0 + sk8, &As[r * 32]);
            async_ld16(Bt + (size_t)(col0 + r + srow) * 256 + k0 + sk8, &Bs[r * 32]);
        }
        __syncthreads();

        bf16x8 af[4], bfr[4];
        const int mrow = lane & 15;
        const int kq   = (lane >> 4) * 8;
        #pragma unroll
        for (int i = 0; i < 4; i++) {
            af[i]  = *(const bf16x8*)&As[(wr + i * 16 + mrow) * 32 + kq];
            bfr[i] = *(const bf16x8*)&Bs[(wc + i * 16 + mrow) * 32 + kq];
        }
        #pragma unroll
        for (int i = 0; i < 4; i++)
            #pragma unroll
            for (int j = 0; j < 4; j++)
                acc[i][j] = __builtin_amdgcn_mfma_f32_16x16x32_bf16(
                    af[i], bfr[j], acc[i][j], 0, 0, 0);
        __syncthreads();
    }

    const float* bp = z ? ((col0 < 128) ? b_attn : b_off) : b_val;
    const int cofs  = (z && col0 >= 128) ? 128 : 0;

    #pragma unroll
    for (int i = 0; i < 4; i++) {
        const int rbase = row0 + wr + i * 16 + ((lane >> 4) << 2);
        #pragma unroll
        for (int j = 0; j < 4; j++) {
            const int col = col0 + wc + j * 16 + (lane & 15);
            const float bb = bp[col - cofs];
            #pragma unroll
            for (int r = 0; r < 4; r++) {
                const int row = rbase + r;
                if (row < MREAL) {
                    const float val = acc[i][j][r] + bb;
                    if (z) {
                        lo_ws[(size_t)row * 384 + col] = val;
                    } else {
                        // head-major v: (n, head, s, ch)
                        const int nn = row / SN;
                        const int s  = row - nn * SN;
                        const int head = col >> 5, ch = col & 31;
                        v_bf[(((size_t)nn * 8 + head) * SN + s) * 32 + ch] = f2bf(val);
                    }
                }
            }
        }
    }
}

// ---------------------------------------------------------------------------
// Out GEMM (R5 LDS structure): out = mdv(bf16) @ wt_out^T + b_out (fp32).
// ---------------------------------------------------------------------------
__global__ __launch_bounds__(256) void gemm_out(
    const ushortT* __restrict__ A, const ushortT* __restrict__ Bt,
    const float* __restrict__ bias, float* __restrict__ C)
{
    __shared__ __attribute__((aligned(16))) ushortT As[128 * 32];
    __shared__ __attribute__((aligned(16))) ushortT Bs[128 * 32];

    const int tid  = threadIdx.x;
    const int wave = tid >> 6;
    const int lane = tid & 63;
    const int row0 = blockIdx.y * 128;
    const int col0 = blockIdx.x * 128;
    const int wr = (wave >> 1) * 64;
    const int wc = (wave & 1) * 64;

    f32x4 acc[4][4];
    #pragma unroll
    for (int i = 0; i < 4; i++)
        #pragma unroll
        for (int j = 0; j < 4; j++)
            acc[i][j] = (f32x4)0.f;

    const int srow = (lane >> 2);
    const int sk8  = (lane & 3) * 8;

    for (int k0 = 0; k0 < 256; k0 += 32) {
        #pragma unroll
        for (int j = 0; j < 2; j++) {
            const int r = wave * 32 + j * 16;
            async_ld16(A  + (size_t)(row0 + r + srow) * 256 + k0 + sk8, &As[r * 32]);
            async_ld16(Bt + (size_t)(col0 + r + srow) * 256 + k0 + sk8, &Bs[r * 32]);
        }
        __syncthreads();

        bf16x8 af[4], bfr[4];
        const int mrow = lane & 15;
        const int kq   = (lane >> 4) * 8;
        #pragma unroll
        for (int i = 0; i < 4; i++) {
            af[i]  = *(const bf16x8*)&As[(wr + i * 16 + mrow) * 32 + kq];
            bfr[i] = *(const bf16x8*)&Bs[(wc + i * 16 + mrow) * 32 + kq];
        }
        #pragma unroll
        for (int i = 0; i < 4; i++)
            #pragma unroll
            for (int j = 0; j < 4; j++)
                acc[i][j] = __builtin_amdgcn_mfma_f32_16x16x32_bf16(
                    af[i], bfr[j], acc[i][j], 0, 0, 0);
        __syncthreads();
    }

    #pragma unroll
    for (int i = 0; i < 4; i++) {
        const int rbase = row0 + wr + i * 16 + ((lane >> 4) << 2);
        #pragma unroll
        for (int j = 0; j < 4; j++) {
            const int col = col0 + wc + j * 16 + (lane & 15);
            const float bb = bias[col];
            #pragma unroll
            for (int r = 0; r < 4; r++) {
                const int row = rbase + r;
                if (row < MREAL)
                    C[(size_t)row * 256 + col] = acc[i][j][r] + bb;
            }
        }
    }
}

// ---------------------------------------------------------------------------
// Per-head two-phase sample kernel. Block = 256 threads = 4 waves =
// 32 queries of ONE head (grid: 383 x 8 heads x 2 batch; tail clamps q,
// duplicate writes of identical values are benign).
// R4: phase 2 is a 2-deep software pipeline over the 4 point-groups with
// __builtin_amdgcn_sched_barrier(0) fences. Loads cannot sink below a
// fence, so 16-32 gathers are genuinely in flight per wave (the R1-R3
// versions measured VGPR=36-48: the scheduler had been serializing the
// loads to ~4 in flight, capping memory-level parallelism at ~70
// requests/CU -- the invariant 58-61 us across all structural variants).
// Target: ~350 requests/CU in flight. VGPR is expected at ~100-130 (the
// proof-of-materialization counter), occupancy 4 waves/SIMD.
// ---------------------------------------------------------------------------
__global__ __launch_bounds__(256) void sample_kernel(
    const float* __restrict__ lo,       // (N*Q, 384): [0,128) logits, [128,384) off
    const float* __restrict__ geom,     // (N*Q, 4)
    const ushortT* __restrict__ v,      // (N, 8, S, 32) bf16 head-major
    ushortT* __restrict__ out)          // (N*Q, 256) bf16 mdv
{
    const int tid  = threadIdx.x;
    const int w    = tid >> 6;          // wave 0..3
    const int lane = tid & 63;
    const int qi   = lane >> 3;         // query within wave's 8
    const int m    = blockIdx.y;        // head
    const int n    = blockIdx.z;
    int q = blockIdx.x * 32 + w * 8 + qi;
    q = min(q, QN - 1);                 // tail clamp (duplicates are benign)

    // per query: 16 points * 12 ints + 4 pad = 196 ints (stride = 4 banks)
    __shared__ __attribute__((aligned(16))) int pls[4][1568];   // 25088 B

    const size_t qb = (size_t)n * QN + q;

    // ---- phase 1 ----
    {
        const int p = lane & 7;                  // point pair 0..7
        const float* lorow = lo + qb * 384;
        const float2 lg = *(const float2*)(lorow + m * 16 + p * 2);
        const float4 of = *(const float4*)(lorow + 128 + m * 32 + p * 4);
        const float4 g  = *(const float4*)(geom + qb * 4);

        float mx = fmaxf(lg.x, lg.y);
        mx = fmaxf(mx, __shfl_xor(mx, 1));
        mx = fmaxf(mx, __shfl_xor(mx, 2));
        mx = fmaxf(mx, __shfl_xor(mx, 4));
        const float e0 = __expf(lg.x - mx);
        const float e1 = __expf(lg.y - mx);
        float s = e0 + e1;
        s += __shfl_xor(s, 1);
        s += __shfl_xor(s, 2);
        s += __shfl_xor(s, 4);
        const float inv = 1.f / s;

        const int l  = p >> 1;
        const int Wl = 96 >> l;
        const int s0 = (l == 0) ? 0 : (l == 1) ? 9216 : (l == 2) ? 11520 : 12096;
        const float cx = g.x, cy = g.y;
        const float sx = g.z * 0.125f, sy = g.w * 0.125f;
        // record for point pt = t*8 + p lives at qi*196 + pt*12
        int* myrec = &pls[w][qi * 196 + p * 12];

        #pragma unroll
        for (int t = 0; t < 2; t++) {
            const float ox = t ? of.z : of.x;
            const float oy = t ? of.w : of.y;
            const float wa = (t ? e1 : e0) * inv;

            const float x = (cx + ox * sx) * (float)Wl - 0.5f;
            const float y = (cy + oy * sy) * (float)Wl - 0.5f;
            const float xf = floorf(x), yf = floorf(y);
            const int x0 = (int)xf, y0 = (int)yf;
            const float wx = x - xf, wy = y - yf;

            const bool vx0 = (x0 >= 0) & (x0 < Wl);
            const bool vx1 = (x0 + 1 >= 0) & (x0 + 1 < Wl);
            const bool vy0 = (y0 >= 0) & (y0 < Wl);
            const bool vy1 = (y0 + 1 >= 0) & (y0 + 1 < Wl);

            const float w00 = (vx0 & vy0) ? wa * (1.f - wx) * (1.f - wy) : 0.f;
            const float w10 = (vx1 & vy0) ? wa * wx * (1.f - wy) : 0.f;
            const float w01 = (vx0 & vy1) ? wa * (1.f - wx) * wy : 0.f;
            const float w11 = (vx1 & vy1) ? wa * wx * wy : 0.f;

            const int xc0 = min(max(x0, 0), Wl - 1);
            const int xc1 = min(max(x0 + 1, 0), Wl - 1);
            const int yc0 = min(max(y0, 0), Wl - 1);
            const int yc1 = min(max(y0 + 1, 0), Wl - 1);

            const int o00 = (s0 + yc0 * Wl + xc0) << 6;     // byte off, row 64B
            const int dx  = (xc1 - xc0) << 6;               // 0 or 64
            const int dy  = ((yc1 - yc0) * Wl) << 6;        // 0..6144

            int4 offs;
            offs.x = o00;
            offs.y = o00 + dx;
            offs.z = o00 + dy;
            offs.w = o00 + dy + dx;
            float4 wab, wcd;
            wab.x = w00; wab.y = w00; wab.z = w10; wab.w = w10;
            wcd.x = w01; wcd.y = w01; wcd.z = w11; wcd.w = w11;

            int* rp = myrec + t * 96;       // pt = t*8 + p
            *(int4*)rp = offs;
            *(float4*)(rp + 4) = wab;
            *(float4*)(rp + 8) = wcd;
        }
    }
    __syncthreads();

    // ---- phase 2: 2-deep pipelined gather ----
    const int c  = lane & 7;            // channel quad within head
    const unsigned c8 = (unsigned)(c * 8);
    const unsigned char* vp = (const unsigned char*)
        (v + ((size_t)(n * 8 + m) * SN) * 32);              // uniform base
    const int* grec = &pls[w][qi * 196];

    f32x2 acc01 = (f32x2)0.f, acc23 = (f32x2)0.f;

#define GOFFS(G, O0,O1,O2,O3) \
    const int4 O0 = *(const int4*)(grec + ((G)*4+0)*12); \
    const int4 O1 = *(const int4*)(grec + ((G)*4+1)*12); \
    const int4 O2 = *(const int4*)(grec + ((G)*4+2)*12); \
    const int4 O3 = *(const int4*)(grec + ((G)*4+3)*12);

#define GISSUE(O, U0,U1,U2,U3) \
    const uint2 U0 = *(const uint2*)(vp + ((unsigned)(O).x + c8)); \
    const uint2 U1 = *(const uint2*)(vp + ((unsigned)(O).y + c8)); \
    const uint2 U2 = *(const uint2*)(vp + ((unsigned)(O).z + c8)); \
    const uint2 U3 = *(const uint2*)(vp + ((unsigned)(O).w + c8));

#define GCONSUME(G, R, U0,U1,U2,U3) { \
    const f32x2* wp = (const f32x2*)(grec + ((G)*4+(R))*12 + 4); \
    const f32x2 wA = wp[0], wB = wp[1], wC = wp[2], wD = wp[3]; \
    f32x2 t; \
    t.x = bf_lo(U0.x); t.y = bf_hi(U0.x); acc01 += wA * t; \
    t.x = bf_lo(U0.y); t.y = bf_hi(U0.y); acc23 += wA * t; \
    t.x = bf_lo(U1.x); t.y = bf_hi(U1.x); acc01 += wB * t; \
    t.x = bf_lo(U1.y); t.y = bf_hi(U1.y); acc23 += wB * t; \
    t.x = bf_lo(U2.x); t.y = bf_hi(U2.x); acc01 += wC * t; \
    t.x = bf_lo(U2.y); t.y = bf_hi(U2.y); acc23 += wC * t; \
    t.x = bf_lo(U3.x); t.y = bf_hi(U3.x); acc01 += wD * t; \
    t.x = bf_lo(U3.y); t.y = bf_hi(U3.y); acc23 += wD * t; }

    // prologue: fill pipeline with groups 0 and 1 (32 loads in flight)
    GOFFS(0, oa0,oa1,oa2,oa3)
    GISSUE(oa0, a00,a01,a02,a03)
    GISSUE(oa1, a10,a11,a12,a13)
    GISSUE(oa2, a20,a21,a22,a23)
    GISSUE(oa3, a30,a31,a32,a33)
    GOFFS(1, ob0,ob1,ob2,ob3)
    GISSUE(ob0, b00,b01,b02,b03)
    GISSUE(ob1, b10,b11,b12,b13)
    GISSUE(ob2, b20,b21,b22,b23)
    GISSUE(ob3, b30,b31,b32,b33)
    __builtin_amdgcn_sched_barrier(0);

    // steady state: consume g, refill g+2
    GCONSUME(0,0, a00,a01,a02,a03)
    GCONSUME(0,1, a10,a11,a12,a13)
    GCONSUME(0,2, a20,a21,a22,a23)
    GCONSUME(0,3, a30,a31,a32,a33)
    GOFFS(2, oc0,oc1,oc2,oc3)
    GISSUE(oc0, c00,c01,c02,c03)
    GISSUE(oc1, c10,c11,c12,c13)
    GISSUE(oc2, c20,c21,c22,c23)
    GISSUE(oc3, c30,c31,c32,c33)
    __builtin_amdgcn_sched_barrier(0);

    GCONSUME(1,0, b00,b01,b02,b03)
    GCONSUME(1,1, b10,b11,b12,b13)
    GCONSUME(1,2, b20,b21,b22,b23)
    GCONSUME(1,3, b30,b31,b32,b33)
    GOFFS(3, od0,od1,od2,od3)
    GISSUE(od0, d00,d01,d02,d03)
    GISSUE(od1, d10,d11,d12,d13)
    GISSUE(od2, d20,d21,d22,d23)
    GISSUE(od3, d30,d31,d32,d33)
    __builtin_amdgcn_sched_barrier(0);

    // epilogue
    GCONSUME(2,0, c00,c01,c02,c03)
    GCONSUME(2,1, c10,c11,c12,c13)
    GCONSUME(2,2, c20,c21,c22,c23)
    GCONSUME(2,3, c30,c31,c32,c33)
    GCONSUME(3,0, d00,d01,d02,d03)
    GCONSUME(3,1, d10,d11,d12,d13)
    GCONSUME(3,2, d20,d21,d22,d23)
    GCONSUME(3,3, d30,d31,d32,d33)

#undef GOFFS
#undef GISSUE
#undef GCONSUME

    ushort4 o;
    o.x = f2bf(acc01.x); o.y = f2bf(acc01.y); o.z = f2bf(acc23.x); o.w = f2bf(acc23.y);
    *(ushort4*)(out + qb * 256 + m * 32 + c * 4) = o;
}

// ---------------------------------------------------------------------------
extern "C" void kernel_launch(void* const* d_in, const int* in_sizes, int n_in,
                              void* d_out, int out_size, void* d_ws, size_t ws_size,
                              hipStream_t stream)
{
    const float* queries = (const float*)d_in[0];
    const float* geom    = (const float*)d_in[1];
    const float* src     = (const float*)d_in[2];
    const float* W_off   = (const float*)d_in[3];
    const float* b_off   = (const float*)d_in[4];
    const float* W_attn  = (const float*)d_in[5];
    const float* b_attn  = (const float*)d_in[6];
    const float* W_val   = (const float*)d_in[7];
    const float* b_val   = (const float*)d_in[8];
    const float* W_out   = (const float*)d_in[9];
    const float* b_out   = (const float*)d_in[10];
    float* out = (float*)d_out;

    ushortT* wsb = (ushortT*)d_ws;
    const size_t PADROW = (size_t)MPAD * 256;          // 6,291,456 elems
    ushortT* q_bf    = wsb;
    ushortT* srcmdv  = wsb + PADROW;                   // src_bf, later mdv_bf
    ushortT* v_bf    = wsb + 2 * PADROW;               // head-major v
    ushortT* wt_val  = wsb + 3 * PADROW;               // 256*256
    ushortT* wt_lo   = wt_val + 65536;                 // 384*256
    ushortT* wt_out  = wt_lo + 98304;                  // 256*256
    float* lo_ws = (float*)(wt_out + 65536);           // 24480*384 fp32
    // total ~75.8 MB

    dim3 blk(256);

    cast_all<<<dim3(7016), blk, 0, stream>>>(
        queries, src, W_val, W_attn, W_off, W_out,
        q_bf, srcmdv, wt_val, wt_lo, wt_out);

    // bx<2: v = src@W_val -> v_bf (bf16 head-major); bx>=2: lo -> lo_ws
    gemm_vlo<<<dim3(5, MT), blk, 0, stream>>>(
        q_bf, srcmdv, wt_val, wt_lo, b_val, b_attn, b_off, v_bf, lo_ws);

    sample_kernel<<<dim3((QN + 31) / 32, 8, NB), dim3(256), 0, stream>>>(
        lo_ws, geom, v_bf, srcmdv);

    gemm_out<<<dim3(2, MT), blk, 0, stream>>>(srcmdv, wt_out, b_out, out);
}

// Round 6
// 206.266 us; speedup vs baseline: 1.0104x; 1.0042x over previous
//
#include <hip/hip_runtime.h>
#include <hip/hip_bf16.h>
#include <hip/hip_fp16.h>
#include <cstddef>

// Problem constants
#define NB 2
#define QN 12240
#define SN 12240
#define MREAL 24480          // NB*QN rows
#define MPAD  24576          // 192 * 128
#define MT    192            // M tiles of 128

typedef unsigned short ushortT;
typedef unsigned int uintT;
typedef __bf16 bf16x8 __attribute__((ext_vector_type(8)));
typedef float f32x4 __attribute__((ext_vector_type(4)));
typedef float f32x2 __attribute__((ext_vector_type(2)));
typedef unsigned u32x2v __attribute__((ext_vector_type(2)));

__device__ __forceinline__ ushortT f2bf(float f) {
    uintT u = __float_as_uint(f);
    uintT r = u + 0x7fffu + ((u >> 16) & 1u);   // RNE
    return (ushortT)(r >> 16);
}
__device__ __forceinline__ float bf_lo(uintT u) {   // low bf16 -> f32
    return __uint_as_float(u << 16);
}
__device__ __forceinline__ float bf_hi(uintT u) {   // high bf16 -> f32
    return __uint_as_float(u & 0xffff0000u);
}

__device__ __forceinline__ void async_ld16(const ushortT* g, ushortT* l) {
    __builtin_amdgcn_global_load_lds(
        (const __attribute__((address_space(1))) unsigned int*)g,
        (__attribute__((address_space(3))) unsigned int*)l, 16, 0, 0);
}

// Raw 8B gather the compiler cannot sink/serialize: asm volatile keeps
// issue order among loads and the counted s_waitcnt asm below.
__device__ __forceinline__ u32x2v gload8(const void* base, unsigned voff) {
    u32x2v r;
    asm volatile("global_load_dwordx2 %0, %1, %2"
                 : "=v"(r) : "v"(voff), "s"(base));
    return r;
}

// ---------------------------------------------------------------------------
// Merged cast kernel.
// ---------------------------------------------------------------------------
__global__ __launch_bounds__(256) void cast_all(
    const float* __restrict__ q, const float* __restrict__ src,
    const float* __restrict__ Wval, const float* __restrict__ Wattn,
    const float* __restrict__ Woff, const float* __restrict__ Wout,
    ushortT* __restrict__ qb, ushortT* __restrict__ sb,
    ushortT* __restrict__ tval, ushortT* __restrict__ tlo,
    ushortT* __restrict__ tout)
{
    int bx = blockIdx.x;
    if (bx < 6120) {
        const int issrc = bx >= 3060;
        const size_t idx = ((size_t)(bx - (issrc ? 3060 : 0)) * 256 + threadIdx.x) * 8;
        const float* in = issrc ? src : q;
        ushortT* out = issrc ? sb : qb;
        const float4 a = *(const float4*)(in + idx);
        const float4 b = *(const float4*)(in + idx + 4);
        uint4 o;
        o.x = (uintT)f2bf(a.x) | ((uintT)f2bf(a.y) << 16);
        o.y = (uintT)f2bf(a.z) | ((uintT)f2bf(a.w) << 16);
        o.z = (uintT)f2bf(b.x) | ((uintT)f2bf(b.y) << 16);
        o.w = (uintT)f2bf(b.z) | ((uintT)f2bf(b.w) << 16);
        *(uint4*)(out + idx) = o;
        return;
    }
    bx -= 6120;
    const float* W; ushortT* T; int n, Nw, trow;
    if (bx < 256)      { W = Wval;  T = tval; n = bx;       Nw = 256; trow = n; }
    else if (bx < 384) { W = Wattn; T = tlo;  n = bx - 256; Nw = 128; trow = n; }
    else if (bx < 640) { W = Woff;  T = tlo;  n = bx - 384; Nw = 256; trow = n + 128; }
    else               { W = Wout;  T = tout; n = bx - 640; Nw = 256; trow = n; }
    const int k = threadIdx.x;
    T[(size_t)trow * 256 + k] = f2bf(W[(size_t)k * Nw + n]);
}

// ---------------------------------------------------------------------------
// Fused v + (logits|off) GEMM, LDS-staged (R5 structure), flat grid.
// ---------------------------------------------------------------------------
__global__ __launch_bounds__(256) void gemm_vlo(
    const ushortT* __restrict__ q_bf, const ushortT* __restrict__ src_bf,
    const ushortT* __restrict__ wt_val, const ushortT* __restrict__ wt_lo,
    const float* __restrict__ b_val, const float* __restrict__ b_attn,
    const float* __restrict__ b_off,
    ushortT* __restrict__ v_bf, float* __restrict__ lo_ws)
{
    const int z = blockIdx.x >= 2;
    const int col0 = (z ? blockIdx.x - 2 : blockIdx.x) * 128;

    __shared__ __attribute__((aligned(16))) ushortT As[128 * 32];
    __shared__ __attribute__((aligned(16))) ushortT Bs[128 * 32];

    const ushortT* A  = z ? q_bf : src_bf;
    const ushortT* Bt = z ? wt_lo : wt_val;

    const int tid  = threadIdx.x;
    const int wave = tid >> 6;
    const int lane = tid & 63;
    const int row0 = blockIdx.y * 128;
    const int wr = (wave >> 1) * 64;
    const int wc = (wave & 1) * 64;

    f32x4 acc[4][4];
    #pragma unroll
    for (int i = 0; i < 4; i++)
        #pragma unroll
        for (int j = 0; j < 4; j++)
            acc[i][j] = (f32x4)0.f;

    const int srow = (lane >> 2);
    const int sk8  = (lane & 3) * 8;

    for (int k0 = 0; k0 < 256; k0 += 32) {
        #pragma unroll
        for (int j = 0; j < 2; j++) {
            const int r = wave * 32 + j * 16;
            async_ld16(A  + (size_t)(row0 + r + srow) * 256 + k0 + sk8, &As[r * 32]);
            async_ld16(Bt + (size_t)(col0 + r + srow) * 256 + k0 + sk8, &Bs[r * 32]);
        }
        __syncthreads();

        bf16x8 af[4], bfr[4];
        const int mrow = lane & 15;
        const int kq   = (lane >> 4) * 8;
        #pragma unroll
        for (int i = 0; i < 4; i++) {
            af[i]  = *(const bf16x8*)&As[(wr + i * 16 + mrow) * 32 + kq];
            bfr[i] = *(const bf16x8*)&Bs[(wc + i * 16 + mrow) * 32 + kq];
        }
        #pragma unroll
        for (int i = 0; i < 4; i++)
            #pragma unroll
            for (int j = 0; j < 4; j++)
                acc[i][j] = __builtin_amdgcn_mfma_f32_16x16x32_bf16(
                    af[i], bfr[j], acc[i][j], 0, 0, 0);
        __syncthreads();
    }

    const float* bp = z ? ((col0 < 128) ? b_attn : b_off) : b_val;
    const int cofs  = (z && col0 >= 128) ? 128 : 0;

    #pragma unroll
    for (int i = 0; i < 4; i++) {
        const int rbase = row0 + wr + i * 16 + ((lane >> 4) << 2);
        #pragma unroll
        for (int j = 0; j < 4; j++) {
            const int col = col0 + wc + j * 16 + (lane & 15);
            const float bb = bp[col - cofs];
            #pragma unroll
            for (int r = 0; r < 4; r++) {
                const int row = rbase + r;
                if (row < MREAL) {
                    const float val = acc[i][j][r] + bb;
                    if (z) {
                        lo_ws[(size_t)row * 384 + col] = val;
                    } else {
                        // head-major v: (n, head, s, ch)
                        const int nn = row / SN;
                        const int s  = row - nn * SN;
                        const int head = col >> 5, ch = col & 31;
                        v_bf[(((size_t)nn * 8 + head) * SN + s) * 32 + ch] = f2bf(val);
                    }
                }
            }
        }
    }
}

// ---------------------------------------------------------------------------
// Out GEMM (R5 LDS structure): out = mdv(bf16) @ wt_out^T + b_out (fp32).
// ---------------------------------------------------------------------------
__global__ __launch_bounds__(256) void gemm_out(
    const ushortT* __restrict__ A, const ushortT* __restrict__ Bt,
    const float* __restrict__ bias, float* __restrict__ C)
{
    __shared__ __attribute__((aligned(16))) ushortT As[128 * 32];
    __shared__ __attribute__((aligned(16))) ushortT Bs[128 * 32];

    const int tid  = threadIdx.x;
    const int wave = tid >> 6;
    const int lane = tid & 63;
    const int row0 = blockIdx.y * 128;
    const int col0 = blockIdx.x * 128;
    const int wr = (wave >> 1) * 64;
    const int wc = (wave & 1) * 64;

    f32x4 acc[4][4];
    #pragma unroll
    for (int i = 0; i < 4; i++)
        #pragma unroll
        for (int j = 0; j < 4; j++)
            acc[i][j] = (f32x4)0.f;

    const int srow = (lane >> 2);
    const int sk8  = (lane & 3) * 8;

    for (int k0 = 0; k0 < 256; k0 += 32) {
        #pragma unroll
        for (int j = 0; j < 2; j++) {
            const int r = wave * 32 + j * 16;
            async_ld16(A  + (size_t)(row0 + r + srow) * 256 + k0 + sk8, &As[r * 32]);
            async_ld16(Bt + (size_t)(col0 + r + srow) * 256 + k0 + sk8, &Bs[r * 32]);
        }
        __syncthreads();

        bf16x8 af[4], bfr[4];
        const int mrow = lane & 15;
        const int kq   = (lane >> 4) * 8;
        #pragma unroll
        for (int i = 0; i < 4; i++) {
            af[i]  = *(const bf16x8*)&As[(wr + i * 16 + mrow) * 32 + kq];
            bfr[i] = *(const bf16x8*)&Bs[(wc + i * 16 + mrow) * 32 + kq];
        }
        #pragma unroll
        for (int i = 0; i < 4; i++)
            #pragma unroll
            for (int j = 0; j < 4; j++)
                acc[i][j] = __builtin_amdgcn_mfma_f32_16x16x32_bf16(
                    af[i], bfr[j], acc[i][j], 0, 0, 0);
        __syncthreads();
    }

    #pragma unroll
    for (int i = 0; i < 4; i++) {
        const int rbase = row0 + wr + i * 16 + ((lane >> 4) << 2);
        #pragma unroll
        for (int j = 0; j < 4; j++) {
            const int col = col0 + wc + j * 16 + (lane & 15);
            const float bb = bias[col];
            #pragma unroll
            for (int r = 0; r < 4; r++) {
                const int row = rbase + r;
                if (row < MREAL)
                    C[(size_t)row * 256 + col] = acc[i][j][r] + bb;
            }
        }
    }
}

// ---------------------------------------------------------------------------
// Per-head two-phase sample kernel. Block = 256 threads = 4 waves =
// 32 queries of ONE head (grid: 383 x 8 x 2; tail clamps q, duplicate
// writes of identical values are benign).
// R6 (= R5 intent, fixed macros): phase 2 gathers are ASM VOLATILE
// global_load_dwordx2 with explicit counted s_waitcnt vmcnt(N) +
// sched_barrier(0) after each wait (rule #18 recipe). R1-R4 showed the
// compiler's DAG scheduler sinks plain IR loads to their uses (VGPR
// stayed 36-48), capping MLP at ~4 loads/wave in flight -> ~70
// requests/CU -> the invariant 58-62 us (latency-bound per Little's law).
// Volatile asm order + counted vmcnt keeps 32 loads in flight per wave.
// Expected VGPR ~96-128 (materialization proof), 4 waves/SIMD.
// ---------------------------------------------------------------------------
__global__ __launch_bounds__(256) void sample_kernel(
    const float* __restrict__ lo,       // (N*Q, 384): [0,128) logits, [128,384) off
    const float* __restrict__ geom,     // (N*Q, 4)
    const ushortT* __restrict__ v,      // (N, 8, S, 32) bf16 head-major
    ushortT* __restrict__ out)          // (N*Q, 256) bf16 mdv
{
    const int tid  = threadIdx.x;
    const int w    = tid >> 6;          // wave 0..3
    const int lane = tid & 63;
    const int qi   = lane >> 3;         // query within wave's 8
    const int m    = blockIdx.y;        // head
    const int n    = blockIdx.z;
    int q = blockIdx.x * 32 + w * 8 + qi;
    q = min(q, QN - 1);                 // tail clamp (duplicates are benign)

    // per query: 16 points * 12 ints + 4 pad = 196 ints (stride = 4 banks)
    __shared__ __attribute__((aligned(16))) int pls[4][1568];   // 25088 B

    const size_t qb = (size_t)n * QN + q;

    // ---- phase 1 ----
    {
        const int p = lane & 7;                  // point pair 0..7
        const float* lorow = lo + qb * 384;
        const float2 lg = *(const float2*)(lorow + m * 16 + p * 2);
        const float4 of = *(const float4*)(lorow + 128 + m * 32 + p * 4);
        const float4 g  = *(const float4*)(geom + qb * 4);

        float mx = fmaxf(lg.x, lg.y);
        mx = fmaxf(mx, __shfl_xor(mx, 1));
        mx = fmaxf(mx, __shfl_xor(mx, 2));
        mx = fmaxf(mx, __shfl_xor(mx, 4));
        const float e0 = __expf(lg.x - mx);
        const float e1 = __expf(lg.y - mx);
        float s = e0 + e1;
        s += __shfl_xor(s, 1);
        s += __shfl_xor(s, 2);
        s += __shfl_xor(s, 4);
        const float inv = 1.f / s;

        const int l  = p >> 1;
        const int Wl = 96 >> l;
        const int s0 = (l == 0) ? 0 : (l == 1) ? 9216 : (l == 2) ? 11520 : 12096;
        const float cx = g.x, cy = g.y;
        const float sx = g.z * 0.125f, sy = g.w * 0.125f;
        // record for point pt = t*8 + p lives at qi*196 + pt*12
        int* myrec = &pls[w][qi * 196 + p * 12];

        #pragma unroll
        for (int t = 0; t < 2; t++) {
            const float ox = t ? of.z : of.x;
            const float oy = t ? of.w : of.y;
            const float wa = (t ? e1 : e0) * inv;

            const float x = (cx + ox * sx) * (float)Wl - 0.5f;
            const float y = (cy + oy * sy) * (float)Wl - 0.5f;
            const float xf = floorf(x), yf = floorf(y);
            const int x0 = (int)xf, y0 = (int)yf;
            const float wx = x - xf, wy = y - yf;

            const bool vx0 = (x0 >= 0) & (x0 < Wl);
            const bool vx1 = (x0 + 1 >= 0) & (x0 + 1 < Wl);
            const bool vy0 = (y0 >= 0) & (y0 < Wl);
            const bool vy1 = (y0 + 1 >= 0) & (y0 + 1 < Wl);

            const float w00 = (vx0 & vy0) ? wa * (1.f - wx) * (1.f - wy) : 0.f;
            const float w10 = (vx1 & vy0) ? wa * wx * (1.f - wy) : 0.f;
            const float w01 = (vx0 & vy1) ? wa * (1.f - wx) * wy : 0.f;
            const float w11 = (vx1 & vy1) ? wa * wx * wy : 0.f;

            const int xc0 = min(max(x0, 0), Wl - 1);
            const int xc1 = min(max(x0 + 1, 0), Wl - 1);
            const int yc0 = min(max(y0, 0), Wl - 1);
            const int yc1 = min(max(y0 + 1, 0), Wl - 1);

            const int o00 = (s0 + yc0 * Wl + xc0) << 6;     // byte off, row 64B
            const int dx  = (xc1 - xc0) << 6;               // 0 or 64
            const int dy  = ((yc1 - yc0) * Wl) << 6;        // 0..6144

            int4 offs;
            offs.x = o00;
            offs.y = o00 + dx;
            offs.z = o00 + dy;
            offs.w = o00 + dy + dx;
            float4 wab, wcd;
            wab.x = w00; wab.y = w00; wab.z = w10; wab.w = w10;
            wcd.x = w01; wcd.y = w01; wcd.z = w11; wcd.w = w11;

            int* rp = myrec + t * 96;       // pt = t*8 + p
            *(int4*)rp = offs;
            *(float4*)(rp + 4) = wab;
            *(float4*)(rp + 8) = wcd;
        }
    }
    __syncthreads();

    // ---- phase 2: asm-pipelined gather, 32 loads in flight ----
    const int c  = lane & 7;            // channel quad within head
    const unsigned c8 = (unsigned)(c * 8);
    const unsigned char* vp = (const unsigned char*)
        (v + ((size_t)(n * 8 + m) * SN) * 32);              // uniform base
    const int* grec = &pls[w][qi * 196];

    f32x2 acc01 = (f32x2)0.f, acc23 = (f32x2)0.f;

#define GISSUE(O, U0,U1,U2,U3) \
    u32x2v U0 = gload8(vp, (unsigned)(O).x + c8); \
    u32x2v U1 = gload8(vp, (unsigned)(O).y + c8); \
    u32x2v U2 = gload8(vp, (unsigned)(O).z + c8); \
    u32x2v U3 = gload8(vp, (unsigned)(O).w + c8);

#define GCONS(IDX, U0,U1,U2,U3) { \
    const f32x2* wp = (const f32x2*)(grec + (IDX)*12 + 4); \
    const f32x2 wA = wp[0], wB = wp[1], wC = wp[2], wD = wp[3]; \
    f32x2 t; \
    t.x = bf_lo(U0.x); t.y = bf_hi(U0.x); acc01 += wA * t; \
    t.x = bf_lo(U0.y); t.y = bf_hi(U0.y); acc23 += wA * t; \
    t.x = bf_lo(U1.x); t.y = bf_hi(U1.x); acc01 += wB * t; \
    t.x = bf_lo(U1.y); t.y = bf_hi(U1.y); acc23 += wB * t; \
    t.x = bf_lo(U2.x); t.y = bf_hi(U2.x); acc01 += wC * t; \
    t.x = bf_lo(U2.y); t.y = bf_hi(U2.y); acc23 += wC * t; \
    t.x = bf_lo(U3.x); t.y = bf_hi(U3.x); acc01 += wD * t; \
    t.x = bf_lo(U3.y); t.y = bf_hi(U3.y); acc23 += wD * t; }

#define VMWAIT16 asm volatile("s_waitcnt vmcnt(16)"); __builtin_amdgcn_sched_barrier(0);
#define VMWAIT0  asm volatile("s_waitcnt vmcnt(0)");  __builtin_amdgcn_sched_barrier(0);

    // prologue: groups 0 and 1 in flight (32 loads)
    const int4 oa0 = *(const int4*)(grec + 0 * 12);
    const int4 oa1 = *(const int4*)(grec + 1 * 12);
    const int4 oa2 = *(const int4*)(grec + 2 * 12);
    const int4 oa3 = *(const int4*)(grec + 3 * 12);
    GISSUE(oa0, a0u,a1u,a2u,a3u)
    GISSUE(oa1, b0u,b1u,b2u,b3u)
    GISSUE(oa2, c0u,c1u,c2u,c3u)
    GISSUE(oa3, d0u,d1u,d2u,d3u)
    const int4 ob0 = *(const int4*)(grec + 4 * 12);
    const int4 ob1 = *(const int4*)(grec + 5 * 12);
    const int4 ob2 = *(const int4*)(grec + 6 * 12);
    const int4 ob3 = *(const int4*)(grec + 7 * 12);
    GISSUE(ob0, e0u,e1u,e2u,e3u)
    GISSUE(ob1, f0u,f1u,f2u,f3u)
    GISSUE(ob2, g0u,g1u,g2u,g3u)
    GISSUE(ob3, h0u,h1u,h2u,h3u)

    VMWAIT16                         // g0 retired, g1 in flight
    GCONS(0, a0u,a1u,a2u,a3u)
    GCONS(1, b0u,b1u,b2u,b3u)
    GCONS(2, c0u,c1u,c2u,c3u)
    GCONS(3, d0u,d1u,d2u,d3u)
    const int4 oc0 = *(const int4*)(grec + 8 * 12);
    const int4 oc1 = *(const int4*)(grec + 9 * 12);
    const int4 oc2 = *(const int4*)(grec + 10 * 12);
    const int4 oc3 = *(const int4*)(grec + 11 * 12);
    GISSUE(oc0, i0u,i1u,i2u,i3u)
    GISSUE(oc1, j0u,j1u,j2u,j3u)
    GISSUE(oc2, k0u,k1u,k2u,k3u)
    GISSUE(oc3, l0u,l1u,l2u,l3u)

    VMWAIT16                         // g1 retired, g2 in flight
    GCONS(4, e0u,e1u,e2u,e3u)
    GCONS(5, f0u,f1u,f2u,f3u)
    GCONS(6, g0u,g1u,g2u,g3u)
    GCONS(7, h0u,h1u,h2u,h3u)
    const int4 od0 = *(const int4*)(grec + 12 * 12);
    const int4 od1 = *(const int4*)(grec + 13 * 12);
    const int4 od2 = *(const int4*)(grec + 14 * 12);
    const int4 od3 = *(const int4*)(grec + 15 * 12);
    GISSUE(od0, p0u,p1u,p2u,p3u)
    GISSUE(od1, q0u,q1u,q2u,q3u)
    GISSUE(od2, r0u,r1u,r2u,r3u)
    GISSUE(od3, s0u,s1u,s2u,s3u)

    VMWAIT16                         // g2 retired, g3 in flight
    GCONS(8,  i0u,i1u,i2u,i3u)
    GCONS(9,  j0u,j1u,j2u,j3u)
    GCONS(10, k0u,k1u,k2u,k3u)
    GCONS(11, l0u,l1u,l2u,l3u)

    VMWAIT0                          // g3 retired
    GCONS(12, p0u,p1u,p2u,p3u)
    GCONS(13, q0u,q1u,q2u,q3u)
    GCONS(14, r0u,r1u,r2u,r3u)
    GCONS(15, s0u,s1u,s2u,s3u)

#undef GISSUE
#undef GCONS
#undef VMWAIT16
#undef VMWAIT0

    ushort4 o;
    o.x = f2bf(acc01.x); o.y = f2bf(acc01.y); o.z = f2bf(acc23.x); o.w = f2bf(acc23.y);
    *(ushort4*)(out + qb * 256 + m * 32 + c * 4) = o;
}

// ---------------------------------------------------------------------------
extern "C" void kernel_launch(void* const* d_in, const int* in_sizes, int n_in,
                              void* d_out, int out_size, void* d_ws, size_t ws_size,
                              hipStream_t stream)
{
    const float* queries = (const float*)d_in[0];
    const float* geom    = (const float*)d_in[1];
    const float* src     = (const float*)d_in[2];
    const float* W_off   = (const float*)d_in[3];
    const float* b_off   = (const float*)d_in[4];
    const float* W_attn  = (const float*)d_in[5];
    const float* b_attn  = (const float*)d_in[6];
    const float* W_val   = (const float*)d_in[7];
    const float* b_val   = (const float*)d_in[8];
    const float* W_out   = (const float*)d_in[9];
    const float* b_out   = (const float*)d_in[10];
    float* out = (float*)d_out;

    ushortT* wsb = (ushortT*)d_ws;
    const size_t PADROW = (size_t)MPAD * 256;          // 6,291,456 elems
    ushortT* q_bf    = wsb;
    ushortT* srcmdv  = wsb + PADROW;                   // src_bf, later mdv_bf
    ushortT* v_bf    = wsb + 2 * PADROW;               // head-major v
    ushortT* wt_val  = wsb + 3 * PADROW;               // 256*256
    ushortT* wt_lo   = wt_val + 65536;                 // 384*256
    ushortT* wt_out  = wt_lo + 98304;                  // 256*256
    float* lo_ws = (float*)(wt_out + 65536);           // 24480*384 fp32
    // total ~75.8 MB

    dim3 blk(256);

    cast_all<<<dim3(7016), blk, 0, stream>>>(
        queries, src, W_val, W_attn, W_off, W_out,
        q_bf, srcmdv, wt_val, wt_lo, wt_out);

    // bx<2: v = src@W_val -> v_bf (bf16 head-major); bx>=2: lo -> lo_ws
    gemm_vlo<<<dim3(5, MT), blk, 0, stream>>>(
        q_bf, srcmdv, wt_val, wt_lo, b_val, b_attn, b_off, v_bf, lo_ws);

    sample_kernel<<<dim3((QN + 31) / 32, 8, NB), dim3(256), 0, stream>>>(
        lo_ws, geom, v_bf, srcmdv);

    gemm_out<<<dim3(2, MT), blk, 0, stream>>>(srcmdv, wt_out, b_out, out);
}

// Round 7
// 194.727 us; speedup vs baseline: 1.0702x; 1.0593x over previous
//
#include <hip/hip_runtime.h>
#include <hip/hip_bf16.h>
#include <hip/hip_fp16.h>
#include <cstddef>

// Problem constants
#define NB 2
#define QN 12240
#define SN 12240
#define MREAL 24480          // NB*QN rows
#define MPAD  24576          // 192 * 128
#define MT    192            // M tiles of 128

typedef unsigned short ushortT;
typedef unsigned int uintT;
typedef __bf16 bf16x8 __attribute__((ext_vector_type(8)));
typedef float f32x4 __attribute__((ext_vector_type(4)));
typedef float f32x2 __attribute__((ext_vector_type(2)));

__device__ __forceinline__ ushortT f2bf(float f) {
    uintT u = __float_as_uint(f);
    uintT r = u + 0x7fffu + ((u >> 16) & 1u);   // RNE
    return (ushortT)(r >> 16);
}
__device__ __forceinline__ float bf_lo(uintT u) {   // low bf16 -> f32
    return __uint_as_float(u << 16);
}
__device__ __forceinline__ float bf_hi(uintT u) {   // high bf16 -> f32
    return __uint_as_float(u & 0xffff0000u);
}

__device__ __forceinline__ void async_ld16(const ushortT* g, ushortT* l) {
    __builtin_amdgcn_global_load_lds(
        (const __attribute__((address_space(1))) unsigned int*)g,
        (__attribute__((address_space(3))) unsigned int*)l, 16, 0, 0);
}

// ---------------------------------------------------------------------------
// Merged cast kernel.
// ---------------------------------------------------------------------------
__global__ __launch_bounds__(256) void cast_all(
    const float* __restrict__ q, const float* __restrict__ src,
    const float* __restrict__ Wval, const float* __restrict__ Wattn,
    const float* __restrict__ Woff, const float* __restrict__ Wout,
    ushortT* __restrict__ qb, ushortT* __restrict__ sb,
    ushortT* __restrict__ tval, ushortT* __restrict__ tlo,
    ushortT* __restrict__ tout)
{
    int bx = blockIdx.x;
    if (bx < 6120) {
        const int issrc = bx >= 3060;
        const size_t idx = ((size_t)(bx - (issrc ? 3060 : 0)) * 256 + threadIdx.x) * 8;
        const float* in = issrc ? src : q;
        ushortT* out = issrc ? sb : qb;
        const float4 a = *(const float4*)(in + idx);
        const float4 b = *(const float4*)(in + idx + 4);
        uint4 o;
        o.x = (uintT)f2bf(a.x) | ((uintT)f2bf(a.y) << 16);
        o.y = (uintT)f2bf(a.z) | ((uintT)f2bf(a.w) << 16);
        o.z = (uintT)f2bf(b.x) | ((uintT)f2bf(b.y) << 16);
        o.w = (uintT)f2bf(b.z) | ((uintT)f2bf(b.w) << 16);
        *(uint4*)(out + idx) = o;
        return;
    }
    bx -= 6120;
    const float* W; ushortT* T; int n, Nw, trow;
    if (bx < 256)      { W = Wval;  T = tval; n = bx;       Nw = 256; trow = n; }
    else if (bx < 384) { W = Wattn; T = tlo;  n = bx - 256; Nw = 128; trow = n; }
    else if (bx < 640) { W = Woff;  T = tlo;  n = bx - 384; Nw = 256; trow = n + 128; }
    else               { W = Wout;  T = tout; n = bx - 640; Nw = 256; trow = n; }
    const int k = threadIdx.x;
    T[(size_t)trow * 256 + k] = f2bf(W[(size_t)k * Nw + n]);
}

// ---------------------------------------------------------------------------
// Fused v + (logits|off) GEMM, LDS-staged (R5 structure), flat grid.
// ---------------------------------------------------------------------------
__global__ __launch_bounds__(256) void gemm_vlo(
    const ushortT* __restrict__ q_bf, const ushortT* __restrict__ src_bf,
    const ushortT* __restrict__ wt_val, const ushortT* __restrict__ wt_lo,
    const float* __restrict__ b_val, const float* __restrict__ b_attn,
    const float* __restrict__ b_off,
    ushortT* __restrict__ v_bf, float* __restrict__ lo_ws)
{
    const int z = blockIdx.x >= 2;
    const int col0 = (z ? blockIdx.x - 2 : blockIdx.x) * 128;

    __shared__ __attribute__((aligned(16))) ushortT As[128 * 32];
    __shared__ __attribute__((aligned(16))) ushortT Bs[128 * 32];

    const ushortT* A  = z ? q_bf : src_bf;
    const ushortT* Bt = z ? wt_lo : wt_val;

    const int tid  = threadIdx.x;
    const int wave = tid >> 6;
    const int lane = tid & 63;
    const int row0 = blockIdx.y * 128;
    const int wr = (wave >> 1) * 64;
    const int wc = (wave & 1) * 64;

    f32x4 acc[4][4];
    #pragma unroll
    for (int i = 0; i < 4; i++)
        #pragma unroll
        for (int j = 0; j < 4; j++)
            acc[i][j] = (f32x4)0.f;

    const int srow = (lane >> 2);
    const int sk8  = (lane & 3) * 8;

    for (int k0 = 0; k0 < 256; k0 += 32) {
        #pragma unroll
        for (int j = 0; j < 2; j++) {
            const int r = wave * 32 + j * 16;
            async_ld16(A  + (size_t)(row0 + r + srow) * 256 + k0 + sk8, &As[r * 32]);
            async_ld16(Bt + (size_t)(col0 + r + srow) * 256 + k0 + sk8, &Bs[r * 32]);
        }
        __syncthreads();

        bf16x8 af[4], bfr[4];
        const int mrow = lane & 15;
        const int kq   = (lane >> 4) * 8;
        #pragma unroll
        for (int i = 0; i < 4; i++) {
            af[i]  = *(const bf16x8*)&As[(wr + i * 16 + mrow) * 32 + kq];
            bfr[i] = *(const bf16x8*)&Bs[(wc + i * 16 + mrow) * 32 + kq];
        }
        #pragma unroll
        for (int i = 0; i < 4; i++)
            #pragma unroll
            for (int j = 0; j < 4; j++)
                acc[i][j] = __builtin_amdgcn_mfma_f32_16x16x32_bf16(
                    af[i], bfr[j], acc[i][j], 0, 0, 0);
        __syncthreads();
    }

    const float* bp = z ? ((col0 < 128) ? b_attn : b_off) : b_val;
    const int cofs  = (z && col0 >= 128) ? 128 : 0;

    #pragma unroll
    for (int i = 0; i < 4; i++) {
        const int rbase = row0 + wr + i * 16 + ((lane >> 4) << 2);
        #pragma unroll
        for (int j = 0; j < 4; j++) {
            const int col = col0 + wc + j * 16 + (lane & 15);
            const float bb = bp[col - cofs];
            #pragma unroll
            for (int r = 0; r < 4; r++) {
                const int row = rbase + r;
                if (row < MREAL) {
                    const float val = acc[i][j][r] + bb;
                    if (z) {
                        lo_ws[(size_t)row * 384 + col] = val;
                    } else {
                        // head-major v: (n, head, s, ch)
                        const int nn = row / SN;
                        const int s  = row - nn * SN;
                        const int head = col >> 5, ch = col & 31;
                        v_bf[(((size_t)nn * 8 + head) * SN + s) * 32 + ch] = f2bf(val);
                    }
                }
            }
        }
    }
}

// ---------------------------------------------------------------------------
// Out GEMM (R5 LDS structure): out = mdv(bf16) @ wt_out^T + b_out (fp32).
// ---------------------------------------------------------------------------
__global__ __launch_bounds__(256) void gemm_out(
    const ushortT* __restrict__ A, const ushortT* __restrict__ Bt,
    const float* __restrict__ bias, float* __restrict__ C)
{
    __shared__ __attribute__((aligned(16))) ushortT As[128 * 32];
    __shared__ __attribute__((aligned(16))) ushortT Bs[128 * 32];

    const int tid  = threadIdx.x;
    const int wave = tid >> 6;
    const int lane = tid & 63;
    const int row0 = blockIdx.y * 128;
    const int col0 = blockIdx.x * 128;
    const int wr = (wave >> 1) * 64;
    const int wc = (wave & 1) * 64;

    f32x4 acc[4][4];
    #pragma unroll
    for (int i = 0; i < 4; i++)
        #pragma unroll
        for (int j = 0; j < 4; j++)
            acc[i][j] = (f32x4)0.f;

    const int srow = (lane >> 2);
    const int sk8  = (lane & 3) * 8;

    for (int k0 = 0; k0 < 256; k0 += 32) {
        #pragma unroll
        for (int j = 0; j < 2; j++) {
            const int r = wave * 32 + j * 16;
            async_ld16(A  + (size_t)(row0 + r + srow) * 256 + k0 + sk8, &As[r * 32]);
            async_ld16(Bt + (size_t)(col0 + r + srow) * 256 + k0 + sk8, &Bs[r * 32]);
        }
        __syncthreads();

        bf16x8 af[4], bfr[4];
        const int mrow = lane & 15;
        const int kq   = (lane >> 4) * 8;
        #pragma unroll
        for (int i = 0; i < 4; i++) {
            af[i]  = *(const bf16x8*)&As[(wr + i * 16 + mrow) * 32 + kq];
            bfr[i] = *(const bf16x8*)&Bs[(wc + i * 16 + mrow) * 32 + kq];
        }
        #pragma unroll
        for (int i = 0; i < 4; i++)
            #pragma unroll
            for (int j = 0; j < 4; j++)
                acc[i][j] = __builtin_amdgcn_mfma_f32_16x16x32_bf16(
                    af[i], bfr[j], acc[i][j], 0, 0, 0);
        __syncthreads();
    }

    #pragma unroll
    for (int i = 0; i < 4; i++) {
        const int rbase = row0 + wr + i * 16 + ((lane >> 4) << 2);
        #pragma unroll
        for (int j = 0; j < 4; j++) {
            const int col = col0 + wc + j * 16 + (lane & 15);
            const float bb = bias[col];
            #pragma unroll
            for (int r = 0; r < 4; r++) {
                const int row = rbase + r;
                if (row < MREAL)
                    C[(size_t)row * 256 + col] = acc[i][j][r] + bb;
            }
        }
    }
}

// ---------------------------------------------------------------------------
// Per-head two-phase sample kernel. Block = 256 threads = 4 waves =
// 32 queries of ONE head (grid: 383 x 8 x 2; tail clamps q, duplicate
// writes of identical values are benign).
// R7: HALVED gather instruction count. Five structural variants (R1-R6)
// all measured 58-63 us regardless of scheduling/ILP -> hypothesis: the
// bound is per-CU VMEM instruction processing throughput. Phase-2 lane
// role is now (qi, cr2, c4): cr2 = corner-of-pair, c4 = 16B channel quad.
// Per point each lane issues 2x dwordx4 (corner cr2 and corner 2+cr2, 8
// channels each) instead of 4x dwordx2: 32 gather instrs/wave vs 64,
// same bytes, same fully-consumed 64B lines. Corner partial sums are
// combined once at the end via shfl_xor(...,4).
// If instr-bound: ~45-50 us. If unchanged: line-throughput-bound ->
// pivot to spatial query sorting or declare algorithmic roofline.
// ---------------------------------------------------------------------------
__global__ __launch_bounds__(256) void sample_kernel(
    const float* __restrict__ lo,       // (N*Q, 384): [0,128) logits, [128,384) off
    const float* __restrict__ geom,     // (N*Q, 4)
    const ushortT* __restrict__ v,      // (N, 8, S, 32) bf16 head-major
    ushortT* __restrict__ out)          // (N*Q, 256) bf16 mdv
{
    const int tid  = threadIdx.x;
    const int w    = tid >> 6;          // wave 0..3
    const int lane = tid & 63;
    const int qi   = lane >> 3;         // query within wave's 8
    const int m    = blockIdx.y;        // head
    const int n    = blockIdx.z;
    int q = blockIdx.x * 32 + w * 8 + qi;
    q = min(q, QN - 1);                 // tail clamp (duplicates are benign)

    // per query: 16 points * 12 ints + 4 pad = 196 ints (stride = 4 banks)
    __shared__ __attribute__((aligned(16))) int pls[4][1568];   // 25088 B

    const size_t qb = (size_t)n * QN + q;

    // ---- phase 1 ----
    {
        const int p = lane & 7;                  // point pair 0..7
        const float* lorow = lo + qb * 384;
        const float2 lg = *(const float2*)(lorow + m * 16 + p * 2);
        const float4 of = *(const float4*)(lorow + 128 + m * 32 + p * 4);
        const float4 g  = *(const float4*)(geom + qb * 4);

        float mx = fmaxf(lg.x, lg.y);
        mx = fmaxf(mx, __shfl_xor(mx, 1));
        mx = fmaxf(mx, __shfl_xor(mx, 2));
        mx = fmaxf(mx, __shfl_xor(mx, 4));
        const float e0 = __expf(lg.x - mx);
        const float e1 = __expf(lg.y - mx);
        float s = e0 + e1;
        s += __shfl_xor(s, 1);
        s += __shfl_xor(s, 2);
        s += __shfl_xor(s, 4);
        const float inv = 1.f / s;

        const int l  = p >> 1;
        const int Wl = 96 >> l;
        const int s0 = (l == 0) ? 0 : (l == 1) ? 9216 : (l == 2) ? 11520 : 12096;
        const float cx = g.x, cy = g.y;
        const float sx = g.z * 0.125f, sy = g.w * 0.125f;
        // record for point pt = t*8 + p lives at qi*196 + pt*12
        int* myrec = &pls[w][qi * 196 + p * 12];

        #pragma unroll
        for (int t = 0; t < 2; t++) {
            const float ox = t ? of.z : of.x;
            const float oy = t ? of.w : of.y;
            const float wa = (t ? e1 : e0) * inv;

            const float x = (cx + ox * sx) * (float)Wl - 0.5f;
            const float y = (cy + oy * sy) * (float)Wl - 0.5f;
            const float xf = floorf(x), yf = floorf(y);
            const int x0 = (int)xf, y0 = (int)yf;
            const float wx = x - xf, wy = y - yf;

            const bool vx0 = (x0 >= 0) & (x0 < Wl);
            const bool vx1 = (x0 + 1 >= 0) & (x0 + 1 < Wl);
            const bool vy0 = (y0 >= 0) & (y0 < Wl);
            const bool vy1 = (y0 + 1 >= 0) & (y0 + 1 < Wl);

            const float w00 = (vx0 & vy0) ? wa * (1.f - wx) * (1.f - wy) : 0.f;
            const float w10 = (vx1 & vy0) ? wa * wx * (1.f - wy) : 0.f;
            const float w01 = (vx0 & vy1) ? wa * (1.f - wx) * wy : 0.f;
            const float w11 = (vx1 & vy1) ? wa * wx * wy : 0.f;

            const int xc0 = min(max(x0, 0), Wl - 1);
            const int xc1 = min(max(x0 + 1, 0), Wl - 1);
            const int yc0 = min(max(y0, 0), Wl - 1);
            const int yc1 = min(max(y0 + 1, 0), Wl - 1);

            const int o00 = (s0 + yc0 * Wl + xc0) << 6;     // byte off, row 64B
            const int dx  = (xc1 - xc0) << 6;               // 0 or 64
            const int dy  = ((yc1 - yc0) * Wl) << 6;        // 0..6144

            int4 offs;
            offs.x = o00;           // corner 00 -> weight at rp+4
            offs.y = o00 + dx;      // corner 10 -> weight at rp+6
            offs.z = o00 + dy;      // corner 01 -> weight at rp+8
            offs.w = o00 + dy + dx; // corner 11 -> weight at rp+10
            float4 wab, wcd;
            wab.x = w00; wab.y = w00; wab.z = w10; wab.w = w10;
            wcd.x = w01; wcd.y = w01; wcd.z = w11; wcd.w = w11;

            int* rp = myrec + t * 96;       // pt = t*8 + p
            *(int4*)rp = offs;
            *(float4*)(rp + 4) = wab;
            *(float4*)(rp + 8) = wcd;
        }
    }
    __syncthreads();

    // ---- phase 2: corner-pair dwordx4 gathers (32 instrs/wave) ----
    const int c   = lane & 7;
    const int c4  = c & 3;              // 16B channel quad (8 channels)
    const int cr2 = c >> 2;             // corner of pair: A={00,10}, B={01,11}
    const unsigned c16 = (unsigned)(c4 * 16);
    const unsigned char* vp = (const unsigned char*)
        (v + ((size_t)(n * 8 + m) * SN) * 32);              // uniform base
    const int* grec = &pls[w][qi * 196];
    const int* gw   = grec + 4 + cr2 * 2;   // per-lane weight base

    // 8 channels per lane: acc0={ch0,1}, acc1={ch2,3}, acc2={ch4,5}, acc3={ch6,7}
    f32x2 acc0 = (f32x2)0.f, acc1 = (f32x2)0.f;
    f32x2 acc2 = (f32x2)0.f, acc3 = (f32x2)0.f;

#define ACC8(U, W) { f32x2 t; \
    t.x = bf_lo((U).x); t.y = bf_hi((U).x); acc0 += (W) * t; \
    t.x = bf_lo((U).y); t.y = bf_hi((U).y); acc1 += (W) * t; \
    t.x = bf_lo((U).z); t.y = bf_hi((U).z); acc2 += (W) * t; \
    t.x = bf_lo((U).w); t.y = bf_hi((U).w); acc3 += (W) * t; }

    #pragma unroll
    for (int g = 0; g < 4; g++) {
        const int4 o0 = *(const int4*)(grec + (g * 4 + 0) * 12);
        const int4 o1 = *(const int4*)(grec + (g * 4 + 1) * 12);
        const int4 o2 = *(const int4*)(grec + (g * 4 + 2) * 12);
        const int4 o3 = *(const int4*)(grec + (g * 4 + 3) * 12);

        // per point: corner cr2 (A) and corner 2+cr2 (B), 16B each
        const unsigned a0 = (unsigned)(cr2 ? o0.y : o0.x) + c16;
        const unsigned b0 = (unsigned)(cr2 ? o0.w : o0.z) + c16;
        const unsigned a1 = (unsigned)(cr2 ? o1.y : o1.x) + c16;
        const unsigned b1 = (unsigned)(cr2 ? o1.w : o1.z) + c16;
        const unsigned a2 = (unsigned)(cr2 ? o2.y : o2.x) + c16;
        const unsigned b2 = (unsigned)(cr2 ? o2.w : o2.z) + c16;
        const unsigned a3 = (unsigned)(cr2 ? o3.y : o3.x) + c16;
        const unsigned b3 = (unsigned)(cr2 ? o3.w : o3.z) + c16;

        const uint4 uA0 = *(const uint4*)(vp + a0);
        const uint4 uB0 = *(const uint4*)(vp + b0);
        const uint4 uA1 = *(const uint4*)(vp + a1);
        const uint4 uB1 = *(const uint4*)(vp + b1);
        const uint4 uA2 = *(const uint4*)(vp + a2);
        const uint4 uB2 = *(const uint4*)(vp + b2);
        const uint4 uA3 = *(const uint4*)(vp + a3);
        const uint4 uB3 = *(const uint4*)(vp + b3);

        const f32x2 wA0 = *(const f32x2*)(gw + (g * 4 + 0) * 12);
        const f32x2 wB0 = *(const f32x2*)(gw + (g * 4 + 0) * 12 + 4);
        const f32x2 wA1 = *(const f32x2*)(gw + (g * 4 + 1) * 12);
        const f32x2 wB1 = *(const f32x2*)(gw + (g * 4 + 1) * 12 + 4);
        const f32x2 wA2 = *(const f32x2*)(gw + (g * 4 + 2) * 12);
        const f32x2 wB2 = *(const f32x2*)(gw + (g * 4 + 2) * 12 + 4);
        const f32x2 wA3 = *(const f32x2*)(gw + (g * 4 + 3) * 12);
        const f32x2 wB3 = *(const f32x2*)(gw + (g * 4 + 3) * 12 + 4);

        ACC8(uA0, wA0) ACC8(uB0, wB0)
        ACC8(uA1, wA1) ACC8(uB1, wB1)
        ACC8(uA2, wA2) ACC8(uB2, wB2)
        ACC8(uA3, wA3) ACC8(uB3, wB3)
    }
#undef ACC8

    // combine corner halves: partner lane (lane ^ 4) holds the other 2 corners
    acc0.x += __shfl_xor(acc0.x, 4); acc0.y += __shfl_xor(acc0.y, 4);
    acc1.x += __shfl_xor(acc1.x, 4); acc1.y += __shfl_xor(acc1.y, 4);
    acc2.x += __shfl_xor(acc2.x, 4); acc2.y += __shfl_xor(acc2.y, 4);
    acc3.x += __shfl_xor(acc3.x, 4); acc3.y += __shfl_xor(acc3.y, 4);

    // lane writes 4 of its 8 channels: cr2=0 -> ch {0..3}, cr2=1 -> ch {4..7}
    const f32x2 wlo = cr2 ? acc2 : acc0;
    const f32x2 whi = cr2 ? acc3 : acc1;
    ushort4 o;
    o.x = f2bf(wlo.x); o.y = f2bf(wlo.y); o.z = f2bf(whi.x); o.w = f2bf(whi.y);
    *(ushort4*)(out + qb * 256 + m * 32 + c4 * 8 + cr2 * 4) = o;
}

// ---------------------------------------------------------------------------
extern "C" void kernel_launch(void* const* d_in, const int* in_sizes, int n_in,
                              void* d_out, int out_size, void* d_ws, size_t ws_size,
                              hipStream_t stream)
{
    const float* queries = (const float*)d_in[0];
    const float* geom    = (const float*)d_in[1];
    const float* src     = (const float*)d_in[2];
    const float* W_off   = (const float*)d_in[3];
    const float* b_off   = (const float*)d_in[4];
    const float* W_attn  = (const float*)d_in[5];
    const float* b_attn  = (const float*)d_in[6];
    const float* W_val   = (const float*)d_in[7];
    const float* b_val   = (const float*)d_in[8];
    const float* W_out   = (const float*)d_in[9];
    const float* b_out   = (const float*)d_in[10];
    float* out = (float*)d_out;

    ushortT* wsb = (ushortT*)d_ws;
    const size_t PADROW = (size_t)MPAD * 256;          // 6,291,456 elems
    ushortT* q_bf    = wsb;
    ushortT* srcmdv  = wsb + PADROW;                   // src_bf, later mdv_bf
    ushortT* v_bf    = wsb + 2 * PADROW;               // head-major v
    ushortT* wt_val  = wsb + 3 * PADROW;               // 256*256
    ushortT* wt_lo   = wt_val + 65536;                 // 384*256
    ushortT* wt_out  = wt_lo + 98304;                  // 256*256
    float* lo_ws = (float*)(wt_out + 65536);           // 24480*384 fp32
    // total ~75.8 MB

    dim3 blk(256);

    cast_all<<<dim3(7016), blk, 0, stream>>>(
        queries, src, W_val, W_attn, W_off, W_out,
        q_bf, srcmdv, wt_val, wt_lo, wt_out);

    // bx<2: v = src@W_val -> v_bf (bf16 head-major); bx>=2: lo -> lo_ws
    gemm_vlo<<<dim3(5, MT), blk, 0, stream>>>(
        q_bf, srcmdv, wt_val, wt_lo, b_val, b_attn, b_off, v_bf, lo_ws);

    sample_kernel<<<dim3((QN + 31) / 32, 8, NB), dim3(256), 0, stream>>>(
        lo_ws, geom, v_bf, srcmdv);

    gemm_out<<<dim3(2, MT), blk, 0, stream>>>(srcmdv, wt_out, b_out, out);
}